// Round 14
// baseline (1461.315 us; speedup 1.0000x reference)
//
#include <hip/hip_runtime.h>
#include <hip/hip_bf16.h>
#include <math.h>

#define NTOK   8192      // B*S tokens
#define NEXP   64
#define EMBD   1024
#define MLPD   2048
#define TOPK   2
#define NFLAT  (NTOK * TOPK)
#define BKD    32        // K tile
#define MAXCH  8         // max m-chunks of 128 (mean Me=256)

typedef __attribute__((ext_vector_type(4)))  float  f32x4;
typedef __attribute__((ext_vector_type(2)))  float  f32x2;
typedef __attribute__((ext_vector_type(16))) float  f32x16;
typedef __attribute__((ext_vector_type(8)))  __bf16 bf16x8;

// global -> LDS direct (16B/lane). LDS dest = wave-uniform base + lane*16.
__device__ __forceinline__ void gl16(const void* g, void* lds_base) {
  __builtin_amdgcn_global_load_lds(
      (const __attribute__((address_space(1))) unsigned int*)g,
      (__attribute__((address_space(3))) unsigned int*)lds_base, 16, 0, 0);
}

// ---------------- workspace layout (bytes) ----------------
#define OFF_COUNTS 0
#define OFF_BASE   256
#define OFF_RUN    512
#define OFF_EFLAT  1024
#define OFF_WFLAT  (1024 + 65536)
#define OFF_ROWTOK (1024 + 2 * 65536)
#define OFF_F2R    (1024 + 3 * 65536)
#define OFF_INTER  (1024 + 4 * 65536)                       // bf16 [16384][2048]
#define OFF_OS     (OFF_INTER + (size_t)NFLAT * MLPD * 2)   // out_sorted
#define OFF_XB     OFF_OS   // xb (bf16 x) aliases os: xb dead before gemm2 writes os
#define NEED_F32   (OFF_OS + (size_t)NFLAT * EMBD * 4)

// ---------------- x -> bf16 convert ----------------
__global__ __launch_bounds__(256) void cvt_x_k(const float* __restrict__ x,
                                               __bf16* __restrict__ xb) {
  size_t i = ((size_t)blockIdx.x * 256 + threadIdx.x) * 8;
  f32x4 f0 = *(const f32x4*)(x + i);
  f32x4 f1 = *(const f32x4*)(x + i + 4);
  bf16x8 v;
  #pragma unroll
  for (int q = 0; q < 4; ++q) { v[q] = (__bf16)f0[q]; v[4 + q] = (__bf16)f1[q]; }
  *(bf16x8*)(xb + i) = v;
}

// ---------------- router: logits + top-2 + softmax ----------------
__global__ __launch_bounds__(256) void router_topk(
    const float* __restrict__ x, const float* __restrict__ gk,
    int* __restrict__ e_flat, float* __restrict__ w_flat) {
  int t = blockIdx.x * 4 + (threadIdx.x >> 6);
  int l = threadIdx.x & 63;
  const float* xr = x + (size_t)t * EMBD;
  float acc = 0.f;
  #pragma unroll 8
  for (int i = 0; i < EMBD; ++i)
    acc = fmaf(xr[i], gk[i * NEXP + l], acc);
  float m = acc;
  for (int o = 32; o; o >>= 1) m = fmaxf(m, __shfl_xor(m, o));
  unsigned long long b1 = __ballot(acc == m);
  int i1 = __ffsll(b1) - 1;
  float v2 = (l == i1) ? -INFINITY : acc;
  float m2 = v2;
  for (int o = 32; o; o >>= 1) m2 = fmaxf(m2, __shfl_xor(m2, o));
  unsigned long long b2 = __ballot(v2 == m2);
  int i2 = __ffsll(b2) - 1;
  if (l == 0) {
    float e2 = expf(m2 - m);
    float inv = 1.f / (1.f + e2);
    e_flat[2 * t] = i1;  e_flat[2 * t + 1] = i2;
    w_flat[2 * t] = inv; w_flat[2 * t + 1] = e2 * inv;
  }
}

// ---------------- histogram / scan / scatter ----------------
__global__ void hist_k(const int* __restrict__ ef, int* __restrict__ counts) {
  int j = blockIdx.x * 256 + threadIdx.x;
  if (j < NFLAT) atomicAdd(&counts[ef[j]], 1);
}

__global__ void scan_k(const int* __restrict__ counts, int* __restrict__ base) {
  if (threadIdx.x == 0) {
    int s = 0;
    for (int e = 0; e < NEXP; ++e) { base[e] = s; s += counts[e]; }
  }
}

__global__ void scatter_k(const int* __restrict__ ef, const int* __restrict__ base,
                          int* __restrict__ run, int* __restrict__ rowtok,
                          int* __restrict__ f2r) {
  int j = blockIdx.x * 256 + threadIdx.x;
  if (j < NFLAT) {
    int e = ef[j];
    int r = base[e] + atomicAdd(&run[e], 1);
    f2r[j] = r;
    rowtok[r] = j >> 1;
  }
}

// ---------------- grouped GEMM 1: inter = silu(x@w0) * (x@w1) ----------------
// 128m x 64n x 32k; 4 waves 2x2 (wave 64m x 32n x 2 mats); MFMA 32x32x16.
// BARRIER-FREE: each wave stages ONLY its own operands into its own LDS
// ring-2 region (A via gl16 frag-major; B via 16 b64 -> cvt -> 4 ds_write_b128
// frag-major). All waits are per-wave counted vmcnt(20); waves free-run and
// the CU scheduler overlaps them (TLP latency hiding, no lockstep).
__global__ __launch_bounds__(256, 2) void gemm1_k(
    const __bf16* __restrict__ xb, const float* __restrict__ w0,
    const float* __restrict__ w1, const int* __restrict__ counts,
    const int* __restrict__ base, const int* __restrict__ rowtok,
    __hip_bfloat16* __restrict__ inter) {
  int e = blockIdx.z;
  int Me = counts[e];
  int mc = blockIdx.y;
  if (mc * 128 >= Me) return;
  int rs = base[e];
  int nb = blockIdx.x * 64;
  int t = threadIdx.x;
  int wv = t >> 6, l = t & 63;
  int wr = wv >> 1, wc = wv & 1;
  int lo = l & 31, hi = l >> 5;

  __shared__ __bf16 sh[4][2][4096];   // per wave: 2 bufs x (A 2048 | B 2048)
  __bf16* Aw[2] = { &sh[wv][0][0],    &sh[wv][1][0] };
  __bf16* Bw[2] = { &sh[wv][0][2048], &sh[wv][1][2048] };

  // A: wave stages its OWN rows (wr*64 + g*32 + lo)
  const __bf16* abase[2];
  #pragma unroll
  for (int g = 0; g < 2; ++g) {
    int rga = mc * 128 + wr * 64 + g * 32 + lo;
    rga = rga < Me ? rga : Me - 1;
    abase[g] = xb + (size_t)rowtok[rs + rga] * EMBD + hi * 8;
  }
  // B: lane r=l>>4 -> (mat=r>>1, kh=r&1); cols c0=2*(l&15), c0+1
  int r4 = l >> 4, c0 = 2 * (l & 15);
  int bmat = r4 >> 1, bkh = (r4 & 1) * 16;
  const float* bgb = (bmat ? w1 : w0) + (size_t)e * EMBD * MLPD + nb + wc * 32 + c0;
  int bslot = r4 * 512;

  f32x2 vbA[16], vbB[16];
  f32x16 acc0[2], acc1[2];
  #pragma unroll
  for (int g = 0; g < 2; ++g)
    #pragma unroll
    for (int r = 0; r < 16; ++r) { acc0[g][r] = 0.f; acc1[g][r] = 0.f; }

  const int NT = EMBD / BKD;  // 32 (even)

#define LOADB1(VB, KS)                                                  \
  { int kkc = (KS) * BKD; kkc = kkc < EMBD ? kkc : EMBD - BKD;          \
    _Pragma("unroll")                                                   \
    for (int q = 0; q < 16; ++q)                                        \
      VB[q] = *(const f32x2*)(bgb + (size_t)(kkc + bkh + q) * MLPD); }
#define WRITEB1(VB, BUF)                                                \
  { bf16x8 p0, p1, p2, p3;                                              \
    _Pragma("unroll")                                                   \
    for (int q = 0; q < 8; ++q) {                                       \
      p0[q] = (__bf16)VB[q][0];     p1[q] = (__bf16)VB[8 + q][0];       \
      p2[q] = (__bf16)VB[q][1];     p3[q] = (__bf16)VB[8 + q][1];       \
    }                                                                   \
    *(bf16x8*)&Bw[BUF][bslot + (c0) * 8]          = p0;                 \
    *(bf16x8*)&Bw[BUF][bslot + (32 + c0) * 8]     = p1;                 \
    *(bf16x8*)&Bw[BUF][bslot + (c0 + 1) * 8]      = p2;                 \
    *(bf16x8*)&Bw[BUF][bslot + (32 + c0 + 1) * 8] = p3; }
#define STAGEA1(KS, BUF)                                                \
  { int kkc = (KS) * BKD; kkc = kkc < EMBD ? kkc : EMBD - BKD;          \
    _Pragma("unroll")                                                   \
    for (int g = 0; g < 2; ++g)                                         \
      _Pragma("unroll")                                                 \
      for (int kh = 0; kh < 2; ++kh)                                    \
        gl16(abase[g] + kkc + kh * 16, Aw[BUF] + (g * 2 + kh) * 512); }
#define COMPUTE1(BUF)                                                   \
  { bf16x8 av[2][2], bv0[2], bv1[2];                                    \
    _Pragma("unroll")                                                   \
    for (int g = 0; g < 2; ++g)                                         \
      _Pragma("unroll")                                                 \
      for (int kh = 0; kh < 2; ++kh)                                    \
        av[g][kh] = *(const bf16x8*)&Aw[BUF][(g * 2 + kh) * 512 + l * 8]; \
    _Pragma("unroll")                                                   \
    for (int kh = 0; kh < 2; ++kh) {                                    \
      bv0[kh] = *(const bf16x8*)&Bw[BUF][(0 + kh) * 512 + l * 8];       \
      bv1[kh] = *(const bf16x8*)&Bw[BUF][(2 + kh) * 512 + l * 8];       \
    }                                                                   \
    _Pragma("unroll")                                                   \
    for (int kh = 0; kh < 2; ++kh)                                      \
      _Pragma("unroll")                                                 \
      for (int g = 0; g < 2; ++g) {                                     \
        acc0[g] = __builtin_amdgcn_mfma_f32_32x32x16_bf16(av[g][kh], bv0[kh], acc0[g], 0, 0, 0); \
        acc1[g] = __builtin_amdgcn_mfma_f32_32x32x16_bf16(av[g][kh], bv1[kh], acc1[g], 0, 0, 0); \
      } }
#define G1_ITER(J, SETC, SETO)                                          \
  { LOADB1(SETC, (J) + 2);                                              \
    STAGEA1((J) + 1, ((J) + 1) & 1);                                    \
    asm volatile("s_waitcnt vmcnt(20)" ::: "memory");                   \
    __builtin_amdgcn_sched_barrier(0);                                  \
    WRITEB1(SETO, ((J) + 1) & 1);                                       \
    COMPUTE1((J) & 1); }

  // prologue: B(0)->vbA->LDS buf0; B(1)->vbB; A(0)->buf0
  LOADB1(vbA, 0);
  asm volatile("s_waitcnt vmcnt(0)" ::: "memory");
  WRITEB1(vbA, 0);
  LOADB1(vbB, 1);
  STAGEA1(0, 0);

  for (int j = 0; j < NT; j += 2) {
    G1_ITER(j, vbA, vbB);
    G1_ITER(j + 1, vbB, vbA);
  }
  asm volatile("s_waitcnt vmcnt(0)" ::: "memory");
#undef G1_ITER
#undef COMPUTE1
#undef STAGEA1
#undef WRITEB1
#undef LOADB1

  // epilogue: silu(h0)*h1 -> bf16 inter. 32x32 C map: col=lo, row=(r&3)+8*(r>>2)+4*hi
  #pragma unroll
  for (int g = 0; g < 2; ++g)
    #pragma unroll
    for (int r = 0; r < 16; ++r) {
      int rl = mc * 128 + wr * 64 + g * 32 + (r & 3) + 8 * (r >> 2) + 4 * hi;
      if (rl < Me) {
        float h0 = acc0[g][r], h1 = acc1[g][r];
        float s = h0 / (1.f + expf(-h0)) * h1;
        inter[(size_t)(rs + rl) * MLPD + nb + wc * 32 + lo] = (__hip_bfloat16)s;
      }
    }
}

// ---------------- grouped GEMM 2: out_sorted = inter @ wo ----------------
// Same barrier-free wave-private structure; single B mat; vmcnt(12); NT=64.
template <typename OS_T>
__global__ __launch_bounds__(256, 3) void gemm2_k(
    const __hip_bfloat16* __restrict__ inter, const float* __restrict__ wo,
    const int* __restrict__ counts, const int* __restrict__ base,
    OS_T* __restrict__ os) {
  int e = blockIdx.z;
  int Me = counts[e];
  int mc = blockIdx.y;
  if (mc * 128 >= Me) return;
  int rs = base[e];
  int nb = blockIdx.x * 64;
  int t = threadIdx.x;
  int wv = t >> 6, l = t & 63;
  int wr = wv >> 1, wc = wv & 1;
  int lo = l & 31, hi = l >> 5;

  __shared__ __bf16 sh[4][2][3072];   // per wave: 2 bufs x (A 2048 | B 1024)
  __bf16* Aw[2] = { &sh[wv][0][0],    &sh[wv][1][0] };
  __bf16* Bw[2] = { &sh[wv][0][2048], &sh[wv][1][2048] };

  const __bf16* abase[2];
  #pragma unroll
  for (int g = 0; g < 2; ++g) {
    int rga = mc * 128 + wr * 64 + g * 32 + lo;
    rga = rga < Me ? rga : Me - 1;
    abase[g] = (const __bf16*)inter + (size_t)(rs + rga) * MLPD + hi * 8;
  }
  // B: lane r=l>>4 -> (kh=r>>1, oct=r&1); cols c0=2*(l&15), c0+1
  int r4 = l >> 4, c0 = 2 * (l & 15);
  int bko = (r4 >> 1) * 16 + (r4 & 1) * 8;
  const float* bgb = wo + (size_t)e * MLPD * EMBD + nb + wc * 32 + c0;
  int bkh_slot = (r4 >> 1) * 512, boct = (r4 & 1) * 32;

  f32x2 vbA[8], vbB[8];
  f32x16 acc[2];
  #pragma unroll
  for (int g = 0; g < 2; ++g)
    #pragma unroll
    for (int r = 0; r < 16; ++r) acc[g][r] = 0.f;

  const int NT = MLPD / BKD;  // 64 (even)

#define LOADB2(VB, KS)                                                  \
  { int kkc = (KS) * BKD; kkc = kkc < MLPD ? kkc : MLPD - BKD;          \
    _Pragma("unroll")                                                   \
    for (int q = 0; q < 8; ++q)                                         \
      VB[q] = *(const f32x2*)(bgb + (size_t)(kkc + bko + q) * EMBD); }
#define WRITEB2(VB, BUF)                                                \
  { bf16x8 p0, p1;                                                      \
    _Pragma("unroll")                                                   \
    for (int q = 0; q < 8; ++q) { p0[q] = (__bf16)VB[q][0]; p1[q] = (__bf16)VB[q][1]; } \
    *(bf16x8*)&Bw[BUF][bkh_slot + (boct + c0) * 8]     = p0;            \
    *(bf16x8*)&Bw[BUF][bkh_slot + (boct + c0 + 1) * 8] = p1; }
#define STAGEA2(KS, BUF)                                                \
  { int kkc = (KS) * BKD; kkc = kkc < MLPD ? kkc : MLPD - BKD;          \
    _Pragma("unroll")                                                   \
    for (int g = 0; g < 2; ++g)                                         \
      _Pragma("unroll")                                                 \
      for (int kh = 0; kh < 2; ++kh)                                    \
        gl16(abase[g] + kkc + kh * 16, Aw[BUF] + (g * 2 + kh) * 512); }
#define COMPUTE2(BUF)                                                   \
  { bf16x8 av[2][2], bv[2];                                             \
    _Pragma("unroll")                                                   \
    for (int g = 0; g < 2; ++g)                                         \
      _Pragma("unroll")                                                 \
      for (int kh = 0; kh < 2; ++kh)                                    \
        av[g][kh] = *(const bf16x8*)&Aw[BUF][(g * 2 + kh) * 512 + l * 8]; \
    _Pragma("unroll")                                                   \
    for (int kh = 0; kh < 2; ++kh)                                      \
      bv[kh] = *(const bf16x8*)&Bw[BUF][kh * 512 + l * 8];              \
    _Pragma("unroll")                                                   \
    for (int kh = 0; kh < 2; ++kh)                                      \
      _Pragma("unroll")                                                 \
      for (int g = 0; g < 2; ++g)                                       \
        acc[g] = __builtin_amdgcn_mfma_f32_32x32x16_bf16(av[g][kh], bv[kh], acc[g], 0, 0, 0); }
#define G2_ITER(J, SETC, SETO)                                          \
  { LOADB2(SETC, (J) + 2);                                              \
    STAGEA2((J) + 1, ((J) + 1) & 1);                                    \
    asm volatile("s_waitcnt vmcnt(12)" ::: "memory");                   \
    __builtin_amdgcn_sched_barrier(0);                                  \
    WRITEB2(SETO, ((J) + 1) & 1);                                       \
    COMPUTE2((J) & 1); }

  LOADB2(vbA, 0);
  asm volatile("s_waitcnt vmcnt(0)" ::: "memory");
  WRITEB2(vbA, 0);
  LOADB2(vbB, 1);
  STAGEA2(0, 0);

  for (int j = 0; j < NT; j += 2) {
    G2_ITER(j, vbA, vbB);
    G2_ITER(j + 1, vbB, vbA);
  }
  asm volatile("s_waitcnt vmcnt(0)" ::: "memory");
#undef G2_ITER
#undef COMPUTE2
#undef STAGEA2
#undef WRITEB2
#undef LOADB2

  #pragma unroll
  for (int g = 0; g < 2; ++g)
    #pragma unroll
    for (int r = 0; r < 16; ++r) {
      int rl = mc * 128 + wr * 64 + g * 32 + (r & 3) + 8 * (r >> 2) + 4 * hi;
      if (rl < Me)
        os[(size_t)(rs + rl) * EMBD + nb + wc * 32 + lo] = (OS_T)acc[g][r];
    }
}

// ---------------- combine: out[t] = w1*os[r1] + w2*os[r2] ----------------
template <typename OS_T>
__global__ __launch_bounds__(256) void combine_k(
    const OS_T* __restrict__ os, const int* __restrict__ f2r,
    const float* __restrict__ wf, float* __restrict__ out) {
  int t = blockIdx.x;
  int c = threadIdx.x * 4;
  int r0 = f2r[2 * t], r1 = f2r[2 * t + 1];
  float wa = wf[2 * t], wb = wf[2 * t + 1];
  const OS_T* pa = os + (size_t)r0 * EMBD + c;
  const OS_T* pb = os + (size_t)r1 * EMBD + c;
  float4 o;
  o.x = wa * (float)pa[0] + wb * (float)pb[0];
  o.y = wa * (float)pa[1] + wb * (float)pb[1];
  o.z = wa * (float)pa[2] + wb * (float)pb[2];
  o.w = wa * (float)pa[3] + wb * (float)pb[3];
  *(float4*)(out + (size_t)t * EMBD + c) = o;
}

// ---------------- launcher ----------------
extern "C" void kernel_launch(void* const* d_in, const int* in_sizes, int n_in,
                              void* d_out, int out_size, void* d_ws, size_t ws_size,
                              hipStream_t stream) {
  const float* x  = (const float*)d_in[0];
  const float* gk = (const float*)d_in[1];
  const float* w0 = (const float*)d_in[2];
  const float* w1 = (const float*)d_in[3];
  const float* wo = (const float*)d_in[4];
  float* out = (float*)d_out;
  char* ws = (char*)d_ws;

  int*   counts = (int*)(ws + OFF_COUNTS);
  int*   basep  = (int*)(ws + OFF_BASE);
  int*   run    = (int*)(ws + OFF_RUN);
  int*   ef     = (int*)(ws + OFF_EFLAT);
  float* wfl    = (float*)(ws + OFF_WFLAT);
  int*   rowtok = (int*)(ws + OFF_ROWTOK);
  int*   f2r    = (int*)(ws + OFF_F2R);
  __hip_bfloat16* inter = (__hip_bfloat16*)(ws + OFF_INTER);
  __bf16* xb = (__bf16*)(ws + OFF_XB);   // aliases os region (dead until gemm2)

  hipMemsetAsync(ws, 0, 1024, stream);
  cvt_x_k<<<NTOK * EMBD / (256 * 8), 256, 0, stream>>>(x, xb);
  router_topk<<<NTOK / 4, 256, 0, stream>>>(x, gk, ef, wfl);
  hist_k<<<NFLAT / 256, 256, 0, stream>>>(ef, counts);
  scan_k<<<1, 64, 0, stream>>>(counts, basep);
  scatter_k<<<NFLAT / 256, 256, 0, stream>>>(ef, basep, run, rowtok, f2r);
  gemm1_k<<<dim3(MLPD / 64, MAXCH, NEXP), 256, 0, stream>>>(xb, w0, w1, counts, basep, rowtok, inter);

  if (ws_size >= NEED_F32) {
    float* os = (float*)(ws + OFF_OS);
    gemm2_k<float><<<dim3(EMBD / 64, MAXCH, NEXP), 256, 0, stream>>>(inter, wo, counts, basep, os);
    combine_k<float><<<NTOK, 256, 0, stream>>>(os, f2r, wfl, out);
  } else {
    __hip_bfloat16* os = (__hip_bfloat16*)(ws + OFF_OS);
    gemm2_k<__hip_bfloat16><<<dim3(EMBD / 64, MAXCH, NEXP), 256, 0, stream>>>(inter, wo, counts, basep, os);
    combine_k<__hip_bfloat16><<<NTOK, 256, 0, stream>>>(os, f2r, wfl, out);
  }
}

// Round 15
// 1145.135 us; speedup vs baseline: 1.2761x; 1.2761x over previous
//
#include <hip/hip_runtime.h>
#include <hip/hip_bf16.h>
#include <math.h>

#define NTOK   8192      // B*S tokens
#define NEXP   64
#define EMBD   1024
#define MLPD   2048
#define TOPK   2
#define NFLAT  (NTOK * TOPK)
#define MAXCH  8         // max m-chunks of 128 (mean Me=256)

typedef __attribute__((ext_vector_type(4)))  float  f32x4;
typedef __attribute__((ext_vector_type(2)))  float  f32x2;
typedef __attribute__((ext_vector_type(16))) float  f32x16;
typedef __attribute__((ext_vector_type(8)))  __bf16 bf16x8;

// ---------------- workspace layout (bytes) ----------------
#define OFF_COUNTS 0
#define OFF_BASE   256
#define OFF_RUN    512
#define OFF_EFLAT  1024
#define OFF_WFLAT  (1024 + 65536)
#define OFF_ROWTOK (1024 + 2 * 65536)
#define OFF_F2R    (1024 + 3 * 65536)
#define OFF_INTER  (1024 + 4 * 65536)                       // bf16 [16384][2048]
#define OFF_OS     (OFF_INTER + (size_t)NFLAT * MLPD * 2)   // out_sorted
#define OFF_XB     OFF_OS   // xb (bf16 x) aliases os: xb dead before gemm2 writes os
#define NEED_F32   (OFF_OS + (size_t)NFLAT * EMBD * 4)

// ---------------- x -> bf16 convert ----------------
__global__ __launch_bounds__(256) void cvt_x_k(const float* __restrict__ x,
                                               __bf16* __restrict__ xb) {
  size_t i = ((size_t)blockIdx.x * 256 + threadIdx.x) * 8;
  f32x4 f0 = *(const f32x4*)(x + i);
  f32x4 f1 = *(const f32x4*)(x + i + 4);
  bf16x8 v;
  #pragma unroll
  for (int q = 0; q < 4; ++q) { v[q] = (__bf16)f0[q]; v[4 + q] = (__bf16)f1[q]; }
  *(bf16x8*)(xb + i) = v;
}

// ---------------- router: logits + top-2 + softmax ----------------
__global__ __launch_bounds__(256) void router_topk(
    const float* __restrict__ x, const float* __restrict__ gk,
    int* __restrict__ e_flat, float* __restrict__ w_flat) {
  int t = blockIdx.x * 4 + (threadIdx.x >> 6);
  int l = threadIdx.x & 63;
  const float* xr = x + (size_t)t * EMBD;
  float acc = 0.f;
  #pragma unroll 8
  for (int i = 0; i < EMBD; ++i)
    acc = fmaf(xr[i], gk[i * NEXP + l], acc);
  float m = acc;
  for (int o = 32; o; o >>= 1) m = fmaxf(m, __shfl_xor(m, o));
  unsigned long long b1 = __ballot(acc == m);
  int i1 = __ffsll(b1) - 1;
  float v2 = (l == i1) ? -INFINITY : acc;
  float m2 = v2;
  for (int o = 32; o; o >>= 1) m2 = fmaxf(m2, __shfl_xor(m2, o));
  unsigned long long b2 = __ballot(v2 == m2);
  int i2 = __ffsll(b2) - 1;
  if (l == 0) {
    float e2 = expf(m2 - m);
    float inv = 1.f / (1.f + e2);
    e_flat[2 * t] = i1;  e_flat[2 * t + 1] = i2;
    w_flat[2 * t] = inv; w_flat[2 * t + 1] = e2 * inv;
  }
}

// ---------------- histogram / scan / scatter ----------------
__global__ void hist_k(const int* __restrict__ ef, int* __restrict__ counts) {
  int j = blockIdx.x * 256 + threadIdx.x;
  if (j < NFLAT) atomicAdd(&counts[ef[j]], 1);
}

__global__ void scan_k(const int* __restrict__ counts, int* __restrict__ base) {
  if (threadIdx.x == 0) {
    int s = 0;
    for (int e = 0; e < NEXP; ++e) { base[e] = s; s += counts[e]; }
  }
}

__global__ void scatter_k(const int* __restrict__ ef, const int* __restrict__ base,
                          int* __restrict__ run, int* __restrict__ rowtok,
                          int* __restrict__ f2r) {
  int j = blockIdx.x * 256 + threadIdx.x;
  if (j < NFLAT) {
    int e = ef[j];
    int r = base[e] + atomicAdd(&run[e], 1);
    f2r[j] = r;
    rowtok[r] = j >> 1;
  }
}

// ---------------- grouped GEMM 1: inter = silu(x@w0) * (x@w1) ----------------
// 128m x 64n x 32k; 4 waves 2x2 (wave 64m x 32n); MFMA 32x32x16.
// A: REGISTERS-DIRECT from global (bf16x8 fragment loads, per-lane addresses;
//    2 alternating register sets, loaded 2 steps ahead). No A LDS at all.
// B: reg-staged f32 (2 sets, 2-iter flight) -> cvt -> parity-split frag-major
//    bf16 LDS ring-2 (writes & reads both 2-way conflict-free). 16KB LDS.
// One raw barrier + lgkmcnt(0) per iter; counted vmcnt(12) (no vmcnt(0) drain).
__global__ __launch_bounds__(256, 3) void gemm1_k(
    const __bf16* __restrict__ xb, const float* __restrict__ w0,
    const float* __restrict__ w1, const int* __restrict__ counts,
    const int* __restrict__ base, const int* __restrict__ rowtok,
    __hip_bfloat16* __restrict__ inter) {
  int e = blockIdx.z;
  int Me = counts[e];
  int mc = blockIdx.y;
  if (mc * 128 >= Me) return;
  int rs = base[e];
  int nb = blockIdx.x * 64;
  int t = threadIdx.x;
  int wv = t >> 6, l = t & 63;
  int wr = wv >> 1, wc = wv & 1;
  int lo = l & 31, hi = l >> 5;

  __shared__ __bf16 Bx[2][4096];   // 2 x 8KB [bm2][ko4][par2][np32][8]

  // A fragment bases: wave's own rows (wr*64 + g*32 + lo), k-offset hi*8
  const __bf16* abase[2];
  #pragma unroll
  for (int g = 0; g < 2; ++g) {
    int rga = mc * 128 + wr * 64 + g * 32 + lo;
    rga = rga < Me ? rga : Me - 1;
    abase[g] = xb + (size_t)rowtok[rs + rga] * EMBD + hi * 8;
  }
  // B staging: thread -> (mat, k-octet, col-pair)
  int bm = t >> 7, ko = (t >> 5) & 3, np = t & 31;
  const float* bgb = (bm ? w1 : w0) + (size_t)e * EMBD * MLPD + nb + np * 2;
  int we0 = (((bm * 4 + ko) * 2 + 0) * 32 + np) * 8;
  int we1 = (((bm * 4 + ko) * 2 + 1) * 32 + np) * 8;
  // B read slots (per wave): col c = wc*32+lo -> (par=c&1, np=c>>1), ko=kh*2+hi
  int c_ = wc * 32 + lo;

  f32x2 vbA[8], vbB[8];            // 2 B register sets
  bf16x8 avA[2][2], avB[2][2];     // 2 A register sets [g][kh]
  f32x16 acc0[2], acc1[2];
  #pragma unroll
  for (int g = 0; g < 2; ++g)
    #pragma unroll
    for (int r = 0; r < 16; ++r) { acc0[g][r] = 0.f; acc1[g][r] = 0.f; }

  const int NT = EMBD / 32;  // 32 (even)

#define LOADB1(VB, KS)                                                    \
  { int kkc = (KS) * 32; kkc = kkc < EMBD ? kkc : EMBD - 32;              \
    _Pragma("unroll")                                                     \
    for (int q = 0; q < 8; ++q)                                           \
      VB[q] = *(const f32x2*)(bgb + (size_t)(kkc + ko * 8 + q) * MLPD); }
#define WRITEB1(VB, BUFW)                                                 \
  { bf16x8 c0, c1;                                                        \
    _Pragma("unroll")                                                     \
    for (int q = 0; q < 8; ++q) { c0[q] = (__bf16)VB[q][0]; c1[q] = (__bf16)VB[q][1]; } \
    *(bf16x8*)&Bx[BUFW][we0] = c0;                                        \
    *(bf16x8*)&Bx[BUFW][we1] = c1; }
#define LOADA1(AV, KS)                                                    \
  { int kkc = (KS) * 32; kkc = kkc < EMBD ? kkc : EMBD - 32;              \
    _Pragma("unroll")                                                     \
    for (int g = 0; g < 2; ++g)                                           \
      _Pragma("unroll")                                                   \
      for (int kh = 0; kh < 2; ++kh)                                      \
        AV[g][kh] = *(const bf16x8*)(abase[g] + kkc + kh * 16); }
#define COMPUTE1(AV, BUFC)                                                \
  { bf16x8 bv0[2], bv1[2];                                                \
    _Pragma("unroll")                                                     \
    for (int kh = 0; kh < 2; ++kh) {                                      \
      bv0[kh] = *(const bf16x8*)&Bx[BUFC][(((0 * 4 + kh * 2 + hi) * 2 + (c_ & 1)) * 32 + (c_ >> 1)) * 8]; \
      bv1[kh] = *(const bf16x8*)&Bx[BUFC][(((1 * 4 + kh * 2 + hi) * 2 + (c_ & 1)) * 32 + (c_ >> 1)) * 8]; \
    }                                                                     \
    _Pragma("unroll")                                                     \
    for (int kh = 0; kh < 2; ++kh)                                        \
      _Pragma("unroll")                                                   \
      for (int g = 0; g < 2; ++g) {                                       \
        acc0[g] = __builtin_amdgcn_mfma_f32_32x32x16_bf16(AV[g][kh], bv0[kh], acc0[g], 0, 0, 0); \
        acc1[g] = __builtin_amdgcn_mfma_f32_32x32x16_bf16(AV[g][kh], bv1[kh], acc1[g], 0, 0, 0); \
      } }
// iter J: compute buf BUFC with A set AVC; publish B(J+1) from set VBW into
// BUFW; refill VBW with B(J+3); refill AVC with A(J+2) after compute.
#define G1_ITER(J, VBW, AVC, BUFC, BUFW)                                  \
  { asm volatile("s_waitcnt vmcnt(12)" ::: "memory");                     \
    __builtin_amdgcn_sched_barrier(0);                                    \
    asm volatile("s_waitcnt lgkmcnt(0)" ::: "memory");                    \
    __builtin_amdgcn_sched_barrier(0);                                    \
    __builtin_amdgcn_s_barrier();                                         \
    WRITEB1(VBW, BUFW);                                                   \
    LOADB1(VBW, (J) + 3);                                                 \
    __builtin_amdgcn_sched_barrier(0);                                    \
    COMPUTE1(AVC, BUFC);                                                  \
    LOADA1(AVC, (J) + 2); }

  // prologue: queue order [B(1) 8, A(0) 4, B(2) 8, A(1) 4]
  LOADB1(vbA, 0);
  asm volatile("s_waitcnt vmcnt(0)" ::: "memory");
  WRITEB1(vbA, 0);
  LOADB1(vbB, 1);
  LOADA1(avA, 0);
  LOADB1(vbA, 2);
  LOADA1(avB, 1);

  for (int j = 0; j < NT; j += 2) {
    G1_ITER(j,     vbB, avA, 0, 1);
    G1_ITER(j + 1, vbA, avB, 1, 0);
  }
  asm volatile("s_waitcnt vmcnt(0)" ::: "memory");
#undef G1_ITER
#undef COMPUTE1
#undef LOADA1
#undef WRITEB1
#undef LOADB1

  // epilogue: silu(h0)*h1 -> bf16 inter. 32x32 C map: col=lo, row=(r&3)+8*(r>>2)+4*hi
  #pragma unroll
  for (int g = 0; g < 2; ++g)
    #pragma unroll
    for (int r = 0; r < 16; ++r) {
      int rl = mc * 128 + wr * 64 + g * 32 + (r & 3) + 8 * (r >> 2) + 4 * hi;
      if (rl < Me) {
        float h0 = acc0[g][r], h1 = acc1[g][r];
        float s = h0 / (1.f + expf(-h0)) * h1;
        inter[(size_t)(rs + rl) * MLPD + nb + wc * 32 + lo] = (__hip_bfloat16)s;
      }
    }
}

// ---------------- grouped GEMM 2: out_sorted = inter @ wo ----------------
// Same skeleton, BK=64 (NT=32): A 8 frag loads/wave, B 8 f32x2/thread,
// 8 MFMA/wave/step; vmcnt(16); LDS 2 x 8KB.
template <typename OS_T>
__global__ __launch_bounds__(256, 3) void gemm2_k(
    const __hip_bfloat16* __restrict__ inter, const float* __restrict__ wo,
    const int* __restrict__ counts, const int* __restrict__ base,
    OS_T* __restrict__ os) {
  int e = blockIdx.z;
  int Me = counts[e];
  int mc = blockIdx.y;
  if (mc * 128 >= Me) return;
  int rs = base[e];
  int nb = blockIdx.x * 64;
  int t = threadIdx.x;
  int wv = t >> 6, l = t & 63;
  int wr = wv >> 1, wc = wv & 1;
  int lo = l & 31, hi = l >> 5;

  __shared__ __bf16 Bx[2][4096];   // 2 x 8KB [kq8][par2][np32][8]

  const __bf16* abase[2];
  #pragma unroll
  for (int g = 0; g < 2; ++g) {
    int rga = mc * 128 + wr * 64 + g * 32 + lo;
    rga = rga < Me ? rga : Me - 1;
    abase[g] = (const __bf16*)inter + (size_t)(rs + rga) * MLPD + hi * 8;
  }
  int kq8 = t >> 5, np = t & 31;   // k-octet 0..7 (of 64k), col-pair
  const float* bgb = wo + (size_t)e * MLPD * EMBD + nb + np * 2;
  int we0 = ((kq8 * 2 + 0) * 32 + np) * 8;
  int we1 = ((kq8 * 2 + 1) * 32 + np) * 8;
  int c_ = wc * 32 + lo;

  f32x2 vbA[8], vbB[8];
  bf16x8 avA[2][4], avB[2][4];     // [g][kh] kh 0..3
  f32x16 acc[2];
  #pragma unroll
  for (int g = 0; g < 2; ++g)
    #pragma unroll
    for (int r = 0; r < 16; ++r) acc[g][r] = 0.f;

  const int NT = MLPD / 64;  // 32 (even)

#define LOADB2(VB, KS)                                                    \
  { int kkc = (KS) * 64; kkc = kkc < MLPD ? kkc : MLPD - 64;              \
    _Pragma("unroll")                                                     \
    for (int q = 0; q < 8; ++q)                                           \
      VB[q] = *(const f32x2*)(bgb + (size_t)(kkc + kq8 * 8 + q) * EMBD); }
#define WRITEB2(VB, BUFW)                                                 \
  { bf16x8 c0, c1;                                                        \
    _Pragma("unroll")                                                     \
    for (int q = 0; q < 8; ++q) { c0[q] = (__bf16)VB[q][0]; c1[q] = (__bf16)VB[q][1]; } \
    *(bf16x8*)&Bx[BUFW][we0] = c0;                                        \
    *(bf16x8*)&Bx[BUFW][we1] = c1; }
#define LOADA2(AV, KS)                                                    \
  { int kkc = (KS) * 64; kkc = kkc < MLPD ? kkc : MLPD - 64;              \
    _Pragma("unroll")                                                     \
    for (int g = 0; g < 2; ++g)                                           \
      _Pragma("unroll")                                                   \
      for (int kh = 0; kh < 4; ++kh)                                      \
        AV[g][kh] = *(const bf16x8*)(abase[g] + kkc + kh * 16); }
#define COMPUTE2(AV, BUFC)                                                \
  { bf16x8 bv[4];                                                         \
    _Pragma("unroll")                                                     \
    for (int kh = 0; kh < 4; ++kh)                                        \
      bv[kh] = *(const bf16x8*)&Bx[BUFC][(((kh * 2 + hi) * 2 + (c_ & 1)) * 32 + (c_ >> 1)) * 8]; \
    _Pragma("unroll")                                                     \
    for (int kh = 0; kh < 4; ++kh)                                        \
      _Pragma("unroll")                                                   \
      for (int g = 0; g < 2; ++g)                                         \
        acc[g] = __builtin_amdgcn_mfma_f32_32x32x16_bf16(AV[g][kh], bv[kh], acc[g], 0, 0, 0); }
#define G2_ITER(J, VBW, AVC, BUFC, BUFW)                                  \
  { asm volatile("s_waitcnt vmcnt(16)" ::: "memory");                     \
    __builtin_amdgcn_sched_barrier(0);                                    \
    asm volatile("s_waitcnt lgkmcnt(0)" ::: "memory");                    \
    __builtin_amdgcn_sched_barrier(0);                                    \
    __builtin_amdgcn_s_barrier();                                         \
    WRITEB2(VBW, BUFW);                                                   \
    LOADB2(VBW, (J) + 3);                                                 \
    __builtin_amdgcn_sched_barrier(0);                                    \
    COMPUTE2(AVC, BUFC);                                                  \
    LOADA2(AVC, (J) + 2); }

  LOADB2(vbA, 0);
  asm volatile("s_waitcnt vmcnt(0)" ::: "memory");
  WRITEB2(vbA, 0);
  LOADB2(vbB, 1);
  LOADA2(avA, 0);
  LOADB2(vbA, 2);
  LOADA2(avB, 1);

  for (int j = 0; j < NT; j += 2) {
    G2_ITER(j,     vbB, avA, 0, 1);
    G2_ITER(j + 1, vbA, avB, 1, 0);
  }
  asm volatile("s_waitcnt vmcnt(0)" ::: "memory");
#undef G2_ITER
#undef COMPUTE2
#undef LOADA2
#undef WRITEB2
#undef LOADB2

  #pragma unroll
  for (int g = 0; g < 2; ++g)
    #pragma unroll
    for (int r = 0; r < 16; ++r) {
      int rl = mc * 128 + wr * 64 + g * 32 + (r & 3) + 8 * (r >> 2) + 4 * hi;
      if (rl < Me)
        os[(size_t)(rs + rl) * EMBD + nb + wc * 32 + lo] = (OS_T)acc[g][r];
    }
}

// ---------------- combine: out[t] = w1*os[r1] + w2*os[r2] ----------------
template <typename OS_T>
__global__ __launch_bounds__(256) void combine_k(
    const OS_T* __restrict__ os, const int* __restrict__ f2r,
    const float* __restrict__ wf, float* __restrict__ out) {
  int t = blockIdx.x;
  int c = threadIdx.x * 4;
  int r0 = f2r[2 * t], r1 = f2r[2 * t + 1];
  float wa = wf[2 * t], wb = wf[2 * t + 1];
  const OS_T* pa = os + (size_t)r0 * EMBD + c;
  const OS_T* pb = os + (size_t)r1 * EMBD + c;
  float4 o;
  o.x = wa * (float)pa[0] + wb * (float)pb[0];
  o.y = wa * (float)pa[1] + wb * (float)pb[1];
  o.z = wa * (float)pa[2] + wb * (float)pb[2];
  o.w = wa * (float)pa[3] + wb * (float)pb[3];
  *(float4*)(out + (size_t)t * EMBD + c) = o;
}

// ---------------- launcher ----------------
extern "C" void kernel_launch(void* const* d_in, const int* in_sizes, int n_in,
                              void* d_out, int out_size, void* d_ws, size_t ws_size,
                              hipStream_t stream) {
  const float* x  = (const float*)d_in[0];
  const float* gk = (const float*)d_in[1];
  const float* w0 = (const float*)d_in[2];
  const float* w1 = (const float*)d_in[3];
  const float* wo = (const float*)d_in[4];
  float* out = (float*)d_out;
  char* ws = (char*)d_ws;

  int*   counts = (int*)(ws + OFF_COUNTS);
  int*   basep  = (int*)(ws + OFF_BASE);
  int*   run    = (int*)(ws + OFF_RUN);
  int*   ef     = (int*)(ws + OFF_EFLAT);
  float* wfl    = (float*)(ws + OFF_WFLAT);
  int*   rowtok = (int*)(ws + OFF_ROWTOK);
  int*   f2r    = (int*)(ws + OFF_F2R);
  __hip_bfloat16* inter = (__hip_bfloat16*)(ws + OFF_INTER);
  __bf16* xb = (__bf16*)(ws + OFF_XB);   // aliases os region (dead until gemm2)

  hipMemsetAsync(ws, 0, 1024, stream);
  cvt_x_k<<<NTOK * EMBD / (256 * 8), 256, 0, stream>>>(x, xb);
  router_topk<<<NTOK / 4, 256, 0, stream>>>(x, gk, ef, wfl);
  hist_k<<<NFLAT / 256, 256, 0, stream>>>(ef, counts);
  scan_k<<<1, 64, 0, stream>>>(counts, basep);
  scatter_k<<<NFLAT / 256, 256, 0, stream>>>(ef, basep, run, rowtok, f2r);
  gemm1_k<<<dim3(MLPD / 64, MAXCH, NEXP), 256, 0, stream>>>(xb, w0, w1, counts, basep, rowtok, inter);

  if (ws_size >= NEED_F32) {
    float* os = (float*)(ws + OFF_OS);
    gemm2_k<float><<<dim3(EMBD / 64, MAXCH, NEXP), 256, 0, stream>>>(inter, wo, counts, basep, os);
    combine_k<float><<<NTOK, 256, 0, stream>>>(os, f2r, wfl, out);
  } else {
    __hip_bfloat16* os = (__hip_bfloat16*)(ws + OFF_OS);
    gemm2_k<__hip_bfloat16><<<dim3(EMBD / 64, MAXCH, NEXP), 256, 0, stream>>>(inter, wo, counts, basep, os);
    combine_k<__hip_bfloat16><<<NTOK, 256, 0, stream>>>(os, f2r, wfl, out);
  }
}

// Round 17
// 963.625 us; speedup vs baseline: 1.5165x; 1.1884x over previous
//
#include <hip/hip_runtime.h>
#include <hip/hip_bf16.h>
#include <math.h>

#define NTOK   8192      // B*S tokens
#define NEXP   64
#define EMBD   1024
#define MLPD   2048
#define TOPK   2
#define NFLAT  (NTOK * TOPK)
#define BKD    32        // K tile
#define MAXCH  8         // max m-chunks of 128 (mean Me=256)

typedef __attribute__((ext_vector_type(4)))  float  f32x4;
typedef __attribute__((ext_vector_type(2)))  float  f32x2;
typedef __attribute__((ext_vector_type(16))) float  f32x16;
typedef __attribute__((ext_vector_type(8)))  __bf16 bf16x8;

// global -> LDS direct (16B/lane). LDS dest = wave-uniform base + lane*16.
__device__ __forceinline__ void gl16(const void* g, void* lds_base) {
  __builtin_amdgcn_global_load_lds(
      (const __attribute__((address_space(1))) unsigned int*)g,
      (__attribute__((address_space(3))) unsigned int*)lds_base, 16, 0, 0);
}

// ---------------- workspace layout (bytes) ----------------
#define OFF_COUNTS 0
#define OFF_BASE   256
#define OFF_RUN    512
#define OFF_EFLAT  1024
#define OFF_WFLAT  (1024 + 65536)
#define OFF_ROWTOK (1024 + 2 * 65536)
#define OFF_ROWWT  (1024 + 3 * 65536)
#define OFF_INTER  (1024 + 4 * 65536)                       // bf16 [16384][2048]
#define OFF_XB     (OFF_INTER + (size_t)NFLAT * MLPD * 2)   // bf16 x [8192][1024]

// ---------------- x -> bf16 convert ----------------
__global__ __launch_bounds__(256) void cvt_x_k(const float* __restrict__ x,
                                               __bf16* __restrict__ xb) {
  size_t i = ((size_t)blockIdx.x * 256 + threadIdx.x) * 8;
  f32x4 f0 = *(const f32x4*)(x + i);
  f32x4 f1 = *(const f32x4*)(x + i + 4);
  bf16x8 v;
  #pragma unroll
  for (int q = 0; q < 4; ++q) { v[q] = (__bf16)f0[q]; v[4 + q] = (__bf16)f1[q]; }
  *(bf16x8*)(xb + i) = v;
}

// ---------------- router: logits + top-2 + softmax ----------------
__global__ __launch_bounds__(256) void router_topk(
    const float* __restrict__ x, const float* __restrict__ gk,
    int* __restrict__ e_flat, float* __restrict__ w_flat) {
  int t = blockIdx.x * 4 + (threadIdx.x >> 6);
  int l = threadIdx.x & 63;
  const float* xr = x + (size_t)t * EMBD;
  float acc = 0.f;
  #pragma unroll 8
  for (int i = 0; i < EMBD; ++i)
    acc = fmaf(xr[i], gk[i * NEXP + l], acc);
  float m = acc;
  for (int o = 32; o; o >>= 1) m = fmaxf(m, __shfl_xor(m, o));
  unsigned long long b1 = __ballot(acc == m);
  int i1 = __ffsll(b1) - 1;
  float v2 = (l == i1) ? -INFINITY : acc;
  float m2 = v2;
  for (int o = 32; o; o >>= 1) m2 = fmaxf(m2, __shfl_xor(m2, o));
  unsigned long long b2 = __ballot(v2 == m2);
  int i2 = __ffsll(b2) - 1;
  if (l == 0) {
    float e2 = expf(m2 - m);
    float inv = 1.f / (1.f + e2);
    e_flat[2 * t] = i1;  e_flat[2 * t + 1] = i2;
    w_flat[2 * t] = inv; w_flat[2 * t + 1] = e2 * inv;
  }
}

// ---------------- histogram / scan / scatter ----------------
__global__ void hist_k(const int* __restrict__ ef, int* __restrict__ counts) {
  int j = blockIdx.x * 256 + threadIdx.x;
  if (j < NFLAT) atomicAdd(&counts[ef[j]], 1);
}

__global__ void scan_k(const int* __restrict__ counts, int* __restrict__ base) {
  if (threadIdx.x == 0) {
    int s = 0;
    for (int e = 0; e < NEXP; ++e) { base[e] = s; s += counts[e]; }
  }
}

__global__ void scatter_k(const int* __restrict__ ef, const float* __restrict__ wf,
                          const int* __restrict__ base, int* __restrict__ run,
                          int* __restrict__ rowtok, float* __restrict__ rowwt) {
  int j = blockIdx.x * 256 + threadIdx.x;
  if (j < NFLAT) {
    int e = ef[j];
    int r = base[e] + atomicAdd(&run[e], 1);
    rowtok[r] = j >> 1;
    rowwt[r] = wf[j];
  }
}

// ---------------- grouped GEMM 1: inter = silu(x@w0) * (x@w1) ----------------
// (R11 structure — best measured.) 128m x 64n x 32k; 4 waves 2x2; MFMA 32x32x16.
// A: bf16 gl_lds fragment-major, ring-3, depth-2.
// B: reg-staged f32 -> cvt bf16 -> ds_write_b128 fragment-major, ring-3.
__global__ __launch_bounds__(256, 3) void gemm1_k(
    const __bf16* __restrict__ xb, const float* __restrict__ w0,
    const float* __restrict__ w1, const int* __restrict__ counts,
    const int* __restrict__ base, const int* __restrict__ rowtok,
    __hip_bfloat16* __restrict__ inter) {
  int e = blockIdx.z;
  int Me = counts[e];
  int mc = blockIdx.y;
  if (mc * 128 >= Me) return;
  int rs = base[e];
  int nb = blockIdx.x * 64;
  int t = threadIdx.x;
  int wv = t >> 6, l = t & 63;
  int wr = wv >> 1, wc = wv & 1;
  int lo = l & 31, hi = l >> 5;

  __shared__ __bf16 Ax[3][4096];  // 3 x 8KB [g4][kh2][lane64][8]
  __shared__ __bf16 Bx[3][4096];  // 3 x 8KB [m2][kh2][wc2][lane64][8]

  int rga = mc * 128 + wv * 32 + lo; rga = rga < Me ? rga : Me - 1;
  const __bf16* abase = xb + (size_t)rowtok[rs + rga] * EMBD + hi * 8;
  int bm = t >> 7, ko = (t >> 5) & 3, np = t & 31;
  const float* bgb = (bm ? w1 : w0) + (size_t)e * EMBD * MLPD + nb + np * 2;
  int n0 = np * 2;
  int bslot = ((bm * 2 + (ko >> 1)) * 2 + (n0 >> 5)) * 64 + (ko & 1) * 32 + (n0 & 31);

  f32x2 vb[8];

  auto LOADB = [&](int ks) {
    int kk = ks * BKD;
    #pragma unroll
    for (int j = 0; j < 8; ++j)
      vb[j] = *(const f32x2*)(bgb + (size_t)(kk + ko * 8 + j) * MLPD);
  };
  auto WRITEB = [&](int buf) {
    bf16x8 c0, c1;
    #pragma unroll
    for (int j = 0; j < 8; ++j) { c0[j] = (__bf16)vb[j][0]; c1[j] = (__bf16)vb[j][1]; }
    *(bf16x8*)&Bx[buf][bslot * 8]     = c0;
    *(bf16x8*)&Bx[buf][bslot * 8 + 8] = c1;
  };
  auto STAGEA = [&](int ks, int buf) {
    int kk = ks * BKD;
    #pragma unroll
    for (int kh = 0; kh < 2; ++kh)
      gl16(abase + kk + kh * 16, &Ax[buf][(wv * 2 + kh) * 512]);
  };

  f32x16 acc0[2], acc1[2];
  #pragma unroll
  for (int g = 0; g < 2; ++g)
    #pragma unroll
    for (int r = 0; r < 16; ++r) { acc0[g][r] = 0.f; acc1[g][r] = 0.f; }

  const int NT = EMBD / BKD;  // 32
  LOADB(0);
  asm volatile("s_waitcnt vmcnt(0)" ::: "memory");
  WRITEB(0);
  LOADB(1);
  __builtin_amdgcn_sched_barrier(0);
  STAGEA(0, 0);
  STAGEA(1, 1);   // (R16 bug: this line was missing -> Ax[1] never staged)

  for (int ks = 0; ks < NT; ++ks) {
    int cur = ks % 3;
    if (ks + 1 < NT) asm volatile("s_waitcnt vmcnt(2)" ::: "memory");
    else             asm volatile("s_waitcnt vmcnt(0)" ::: "memory");
    __builtin_amdgcn_sched_barrier(0);
    asm volatile("s_waitcnt lgkmcnt(0)" ::: "memory");
    __builtin_amdgcn_sched_barrier(0);
    __builtin_amdgcn_s_barrier();
    if (ks + 1 < NT) WRITEB((ks + 1) % 3);       // cvt+publish next B tile
    __builtin_amdgcn_sched_barrier(0);
    if (ks + 2 < NT) LOADB(ks + 2);              // B regs fly a full step
    __builtin_amdgcn_sched_barrier(0);
    if (ks + 2 < NT) STAGEA(ks + 2, (ks + 2) % 3);
    __builtin_amdgcn_sched_barrier(0);

    bf16x8 av[2][2], bv0[2], bv1[2];
    #pragma unroll
    for (int g = 0; g < 2; ++g)
      #pragma unroll
      for (int kh = 0; kh < 2; ++kh)
        av[g][kh] = *(const bf16x8*)&Ax[cur][((wr * 2 + g) * 2 + kh) * 512 + l * 8];
    #pragma unroll
    for (int kh = 0; kh < 2; ++kh) {
      bv0[kh] = *(const bf16x8*)&Bx[cur][((0 + kh) * 2 + wc) * 512 + l * 8];
      bv1[kh] = *(const bf16x8*)&Bx[cur][((2 + kh) * 2 + wc) * 512 + l * 8];
    }
    #pragma unroll
    for (int kh = 0; kh < 2; ++kh)
      #pragma unroll
      for (int g = 0; g < 2; ++g) {
        acc0[g] = __builtin_amdgcn_mfma_f32_32x32x16_bf16(av[g][kh], bv0[kh], acc0[g], 0, 0, 0);
        acc1[g] = __builtin_amdgcn_mfma_f32_32x32x16_bf16(av[g][kh], bv1[kh], acc1[g], 0, 0, 0);
      }
  }

  // epilogue: silu(h0)*h1 -> bf16 inter. 32x32 C map: col=lo, row=(r&3)+8*(r>>2)+4*hi
  #pragma unroll
  for (int g = 0; g < 2; ++g)
    #pragma unroll
    for (int r = 0; r < 16; ++r) {
      int rl = mc * 128 + (wr * 2 + g) * 32 + (r & 3) + 8 * (r >> 2) + 4 * hi;
      if (rl < Me) {
        float h0 = acc0[g][r], h1 = acc1[g][r];
        float s = h0 / (1.f + expf(-h0)) * h1;
        inter[(size_t)(rs + rl) * MLPD + nb + wc * 32 + lo] = (__hip_bfloat16)s;
      }
    }
}

// ---------------- grouped GEMM 2 + fused combine ----------------
// (R10 structure, verbatim loop.) Ring-3 gl_lds both operands, counted vmcnt(4),
// ONE barrier per iter. Epilogue: atomicAdd(w * acc) into out[tok] (no os).
__global__ __launch_bounds__(256, 3) void gemm2_k(
    const __hip_bfloat16* __restrict__ inter, const float* __restrict__ wo,
    const int* __restrict__ counts, const int* __restrict__ base,
    const int* __restrict__ rowtok, const float* __restrict__ rowwt,
    float* __restrict__ out) {
  int e = blockIdx.z;
  int Me = counts[e];
  int mc = blockIdx.y;
  if (mc * 128 >= Me) return;
  int rs = base[e];
  int nb = blockIdx.x * 64;
  int t = threadIdx.x;
  int wv = t >> 6, l = t & 63;
  int wr = wv >> 1, wc = wv & 1;
  int lo = l & 31, hi = l >> 5;

  __shared__ __bf16 A2[3][4096];   // 3 x 8KB [slot=g*2+kh][lane][8bf16]
  __shared__ float  B2[3][2048];   // 3 x 8KB [k32][n64]

  int rga = mc * 128 + wv * 32 + lo; rga = rga < Me ? rga : Me - 1;
  const __bf16* abase = (const __bf16*)inter + (size_t)(rs + rga) * MLPD + hi * 8;
  const float* wbase = wo + (size_t)e * MLPD * EMBD + nb + (l & 15) * 4 +
                       (size_t)(l >> 4) * EMBD;

  auto STAGE = [&](int ks, int buf) {
    int kk = ks * BKD;
    #pragma unroll
    for (int kh = 0; kh < 2; ++kh)
      gl16(abase + kk + kh * 16, &A2[buf][(wv * 2 + kh) * 512]);
    #pragma unroll
    for (int j = 0; j < 2; ++j)
      gl16(wbase + (size_t)(kk + wv * 8 + j * 4) * EMBD,
           &B2[buf][(wv * 8 + j * 4) * 64]);
  };

  f32x16 acc[2];
  #pragma unroll
  for (int g = 0; g < 2; ++g)
    #pragma unroll
    for (int r = 0; r < 16; ++r) acc[g][r] = 0.f;

  const int NT = MLPD / BKD;  // 64
  STAGE(0, 0);
  STAGE(1, 1);
  int bufR = 0, bufW = 2;
  for (int ks = 0; ks < NT; ++ks) {
    if (ks + 1 < NT) asm volatile("s_waitcnt vmcnt(4)" ::: "memory");
    else             asm volatile("s_waitcnt vmcnt(0)" ::: "memory");
    __builtin_amdgcn_sched_barrier(0);
    __builtin_amdgcn_s_barrier();
    if (ks + 2 < NT) STAGE(ks + 2, bufW);

    bf16x8 av[2][2];
    #pragma unroll
    for (int g = 0; g < 2; ++g)
      #pragma unroll
      for (int kh = 0; kh < 2; ++kh)
        av[g][kh] = *(const bf16x8*)&A2[bufR][((wr * 2 + g) * 2 + kh) * 512 + l * 8];
    float b[2][8];
    #pragma unroll
    for (int kh = 0; kh < 2; ++kh) {
      int bi = (kh * 16 + hi * 8) * 64 + wc * 32 + lo;
      #pragma unroll
      for (int q = 0; q < 8; ++q) b[kh][q] = B2[bufR][bi + q * 64];
    }
    bf16x8 bv[2];
    #pragma unroll
    for (int kh = 0; kh < 2; ++kh)
      #pragma unroll
      for (int q = 0; q < 8; ++q) bv[kh][q] = (__bf16)b[kh][q];
    #pragma unroll
    for (int kh = 0; kh < 2; ++kh)
      #pragma unroll
      for (int g = 0; g < 2; ++g)
        acc[g] = __builtin_amdgcn_mfma_f32_32x32x16_bf16(av[g][kh], bv[kh], acc[g], 0, 0, 0);
    bufR = bufR == 2 ? 0 : bufR + 1;
    bufW = bufW == 2 ? 0 : bufW + 1;
  }

  // fused combine epilogue: out[tok] += w * acc   (32x32 C map)
  #pragma unroll
  for (int g = 0; g < 2; ++g)
    #pragma unroll
    for (int r = 0; r < 16; ++r) {
      int rl = mc * 128 + (wr * 2 + g) * 32 + (r & 3) + 8 * (r >> 2) + 4 * hi;
      if (rl < Me) {
        int row = rs + rl;
        float wt = rowwt[row];
        atomicAdd(&out[(size_t)rowtok[row] * EMBD + nb + wc * 32 + lo],
                  wt * acc[g][r]);
      }
    }
}

// ---------------- launcher ----------------
extern "C" void kernel_launch(void* const* d_in, const int* in_sizes, int n_in,
                              void* d_out, int out_size, void* d_ws, size_t ws_size,
                              hipStream_t stream) {
  const float* x  = (const float*)d_in[0];
  const float* gk = (const float*)d_in[1];
  const float* w0 = (const float*)d_in[2];
  const float* w1 = (const float*)d_in[3];
  const float* wo = (const float*)d_in[4];
  float* out = (float*)d_out;
  char* ws = (char*)d_ws;

  int*   counts = (int*)(ws + OFF_COUNTS);
  int*   basep  = (int*)(ws + OFF_BASE);
  int*   run    = (int*)(ws + OFF_RUN);
  int*   ef     = (int*)(ws + OFF_EFLAT);
  float* wfl    = (float*)(ws + OFF_WFLAT);
  int*   rowtok = (int*)(ws + OFF_ROWTOK);
  float* rowwt  = (float*)(ws + OFF_ROWWT);
  __hip_bfloat16* inter = (__hip_bfloat16*)(ws + OFF_INTER);
  __bf16* xb = (__bf16*)(ws + OFF_XB);

  hipMemsetAsync(ws, 0, 1024, stream);
  hipMemsetAsync(out, 0, (size_t)NTOK * EMBD * 4, stream);
  cvt_x_k<<<NTOK * EMBD / (256 * 8), 256, 0, stream>>>(x, xb);
  router_topk<<<NTOK / 4, 256, 0, stream>>>(x, gk, ef, wfl);
  hist_k<<<NFLAT / 256, 256, 0, stream>>>(ef, counts);
  scan_k<<<1, 64, 0, stream>>>(counts, basep);
  scatter_k<<<NFLAT / 256, 256, 0, stream>>>(ef, wfl, basep, run, rowtok, rowwt);
  gemm1_k<<<dim3(MLPD / 64, MAXCH, NEXP), 256, 0, stream>>>(xb, w0, w1, counts, basep, rowtok, inter);
  gemm2_k<<<dim3(EMBD / 64, MAXCH, NEXP), 256, 0, stream>>>(inter, wo, counts, basep, rowtok, rowwt, out);
}